// Round 1
// 377.781 us; speedup vs baseline: 1.2464x; 1.2464x over previous
//
#include <hip/hip_runtime.h>
#include <math.h>

#define NTOK 131072
#define KC   1024
#define DIMV 64
#define TPB  64      // tokens per block (one per lane)
#define KPW  256     // codes per wave (KC / 4 waves)

#define OUT_LOSS 0
#define OUT_Q    1
#define OUT_PERP (1 + NTOK * DIMV)
#define OUT_IDX  (2 + NTOK * DIMV)

// numpy pairwise_sum mimic for n=64 of v[i]*v[i]:
// r[0..7] = a[0..7]; for i=8..56 step 8: r[j] += a[i+j];
// res = ((r0+r1)+(r2+r3))+((r4+r5)+(r6+r7))
// contract(off): numpy squares elementwise (rounded) then adds -- no FMA.
__device__ __forceinline__ float sumsq64_np(const float v[DIMV]) {
#pragma clang fp contract(off)
  {
    float r[8];
#pragma unroll
    for (int j = 0; j < 8; ++j) r[j] = v[j] * v[j];
#pragma unroll
    for (int i = 8; i < 64; i += 8) {
#pragma unroll
      for (int j = 0; j < 8; ++j) r[j] += v[i + j] * v[i + j];
    }
    return ((r[0] + r[1]) + (r[2] + r[3])) + ((r[4] + r[5]) + (r[6] + r[7]));
  }
}

__global__ void __launch_bounds__(256)
vq_main_kernel(const float* __restrict__ xin, const float* __restrict__ cb,
               float* __restrict__ out, float* __restrict__ ws_mse,
               unsigned int* __restrict__ ws_hist) {
  __shared__ float s_norm[KC];
  __shared__ unsigned int s_hist[KC];
  __shared__ float s_cd[256];
  __shared__ int   s_ci[256];
  const int tid  = threadIdx.x;
  const int lane = tid & 63;
  // wave id as an explicit scalar so the codebook row address stays
  // wave-uniform -> s_load broadcast path in the argmin loop.
  const int wv = __builtin_amdgcn_readfirstlane(tid >> 6);

  // Codebook norms |e_k|^2 (numpy order) into LDS; also zero LDS histogram.
  for (int k = tid; k < KC; k += 256) {
    float e[DIMV];
    const float4* e4 = reinterpret_cast<const float4*>(cb + k * DIMV);
#pragma unroll
    for (int i = 0; i < 16; ++i) {
      float4 t = e4[i];
      e[4 * i + 0] = t.x; e[4 * i + 1] = t.y;
      e[4 * i + 2] = t.z; e[4 * i + 3] = t.w;
    }
    s_norm[k] = sumsq64_np(e);
    s_hist[k] = 0u;
  }
  __syncthreads();

  // Each block owns 64 tokens; every wave loads the SAME 64 token rows
  // (lane l -> token l), but scans a different quarter of the codebook.
  const int token = blockIdx.x * TPB + lane;

  float x[DIMV];
  const float4* x4 = reinterpret_cast<const float4*>(xin + (long)token * DIMV);
#pragma unroll
  for (int i = 0; i < 16; ++i) {
    float4 t = x4[i];
    x[4 * i + 0] = t.x; x[4 * i + 1] = t.y;
    x[4 * i + 2] = t.z; x[4 * i + 3] = t.w;
  }
  float xx = sumsq64_np(x);

  // Argmin over this wave's 256 codes. Same distance expression / FMA chain
  // order as the verified kernel -> bit-identical d values.
  float best = INFINITY;
  int bidx = 0;
#pragma unroll 1
  for (int kk = 0; kk < KPW; ++kk) {
    const int k = wv * KPW + kk;
    const float* e = cb + k * DIMV;
    float dot = 0.0f;
#pragma unroll
    for (int i = 0; i < DIMV; ++i) dot = __builtin_fmaf(e[i], x[i], dot);
    float d = (xx - 2.0f * dot) + s_norm[k];
    if (d < best) { best = d; bidx = k; }
  }
  s_cd[tid] = best;
  s_ci[tid] = bidx;
  __syncthreads();

  if (wv == 0) {
    // Combine 4 per-wave candidates in ascending code-range order with
    // strict '<' -> exact global first-occurrence argmin.
    float bd = s_cd[lane];
    int   bi = s_ci[lane];
#pragma unroll
    for (int w = 1; w < 4; ++w) {
      float dw = s_cd[w * 64 + lane];
      int   iw = s_ci[w * 64 + lane];
      if (dw < bd) { bd = dw; bi = iw; }
    }
    out[OUT_IDX + token] = (float)bi;
    atomicAdd(&s_hist[bi], 1u);

    // quantized_st = x + (q - x) in fp32 (mimic); mse partial = sum (q-x)^2.
    const float4* q4 = reinterpret_cast<const float4*>(cb + (long)bi * DIMV);
    float acc = 0.0f;
    float4* oq4 = reinterpret_cast<float4*>(out + OUT_Q + (long)token * DIMV);
#pragma unroll
    for (int i = 0; i < 16; ++i) {
      float4 qv = q4[i];
      float d0 = qv.x - x[4 * i + 0];
      float d1 = qv.y - x[4 * i + 1];
      float d2 = qv.z - x[4 * i + 2];
      float d3 = qv.w - x[4 * i + 3];
      float4 o;
      o.x = x[4 * i + 0] + d0;
      o.y = x[4 * i + 1] + d1;
      o.z = x[4 * i + 2] + d2;
      o.w = x[4 * i + 3] + d3;
      acc = __builtin_fmaf(d0, d0, acc);
      acc = __builtin_fmaf(d1, d1, acc);
      acc = __builtin_fmaf(d2, d2, acc);
      acc = __builtin_fmaf(d3, d3, acc);
      oq4[i] = o;
    }
    // Wave-level reduce of the 64 per-token partials, one atomic per block.
#pragma unroll
    for (int off = 32; off > 0; off >>= 1) acc += __shfl_down(acc, off, 64);
    if (lane == 0) atomicAdd(ws_mse, acc);
  }
  __syncthreads();  // s_hist LDS atomics (wave 0) complete before flush

  // Flush LDS histogram to global (device-scope atomics).
  for (int k = tid; k < KC; k += 256) {
    unsigned int c = s_hist[k];
    if (c) atomicAdd(&ws_hist[k], c);
  }
}

__global__ void __launch_bounds__(1024)
vq_final_kernel(const unsigned int* __restrict__ ws_hist,
                const float* __restrict__ ws_mse,
                float* __restrict__ out) {
  __shared__ float s_red[1024];
  const int t = threadIdx.x;
  float p = (float)ws_hist[t] / 131072.0f;         // exact (2^17)
  float term = p * logf(p + 1e-10f);               // p==0 -> 0*log(1e-10)=0
  s_red[t] = term;
  __syncthreads();
#pragma unroll
  for (int s = 512; s > 0; s >>= 1) {
    if (t < s) s_red[t] += s_red[t + s];
    __syncthreads();
  }
  if (t == 0) {
    out[OUT_PERP] = expf(-s_red[0]);
    float mse = ws_mse[0] / 8388608.0f;            // exact (2^23)
    out[OUT_LOSS] = mse + 0.25f * mse;
  }
}

extern "C" void kernel_launch(void* const* d_in, const int* in_sizes, int n_in,
                              void* d_out, int out_size, void* d_ws, size_t ws_size,
                              hipStream_t stream) {
  (void)in_sizes; (void)n_in; (void)out_size; (void)ws_size;
  const float* xin = (const float*)d_in[0];
  const float* cb  = (const float*)d_in[1];
  float* out = (float*)d_out;
  float* ws_mse = (float*)d_ws;                     // [0] : mse sum
  unsigned int* ws_hist = (unsigned int*)d_ws + 1;  // [1..1024] : histogram

  hipMemsetAsync(d_ws, 0, sizeof(float) * (1 + KC), stream);
  hipLaunchKernelGGL(vq_main_kernel, dim3(NTOK / TPB), dim3(256), 0, stream,
                     xin, cb, out, ws_mse, ws_hist);
  hipLaunchKernelGGL(vq_final_kernel, dim3(1), dim3(1024), 0, stream,
                     ws_hist, ws_mse, out);
}

// Round 3
// 256.247 us; speedup vs baseline: 1.8375x; 1.4743x over previous
//
#include <hip/hip_runtime.h>
#include <math.h>

#define NTOK 131072
#define KC   1024
#define DIMV 64
#define TPB  64          // tokens per block (4 waves x 16)
#define NWAVE 4
#define CMAX 192
#define EPS  2e-3f       // > 2*(E1+E2): E1<=3.4e-4 (dropped bf16 cross terms),
                         // E2<=1.5e-5 (reference's two fp32 roundings at |d|~64)
#define NCHUNK 16        // 16 chunks x 4 tiles x 16 codes = 1024 codes

#define OUT_LOSS 0
#define OUT_Q    1
#define OUT_PERP (1 + NTOK * DIMV)
#define OUT_IDX  (2 + NTOK * DIMV)

// workspace floats: [0]=mse, [1..1024]=hist, [1025..2048]=norms;
// packed bf16-hi codebook fragments at byte 12288 (64 tiles x 2KB = 128KB)
#define WS_HIST 1
#define WS_NORM 1025
#define WS_PACK_BYTES 12288
#define WS_NEED (WS_PACK_BYTES + KC * DIMV * 2)   // 143360 bytes

typedef __attribute__((ext_vector_type(8))) short short8;
typedef __attribute__((ext_vector_type(4))) float f32x4;

// numpy pairwise_sum mimic for n=64 of v[i]*v[i] (no FMA) — bit-identical
// to the verified kernel.
__device__ __forceinline__ float sumsq64_np(const float v[DIMV]) {
#pragma clang fp contract(off)
  {
    float r[8];
#pragma unroll
    for (int j = 0; j < 8; ++j) r[j] = v[j] * v[j];
#pragma unroll
    for (int i = 8; i < 64; i += 8) {
#pragma unroll
      for (int j = 0; j < 8; ++j) r[j] += v[i + j] * v[i + j];
    }
    return ((r[0] + r[1]) + (r[2] + r[3])) + ((r[4] + r[5]) + (r[6] + r[7]));
  }
}

__device__ __forceinline__ unsigned short bf16rne(float f) {
  unsigned int u = __float_as_uint(f);
  return (unsigned short)((u + 0x7fffu + ((u >> 16) & 1u)) >> 16);
}

// ---------------- pack: bf16-hi B-fragments + exact norms ------------------
// Tile t holds codes t*16..t*16+15. Lane l of a consuming wave reads code
// t*16+(l&15) with k = f*32 + (l>>4)*8 + j  (B layout of mfma_f32_16x16x32_bf16).
__global__ void __launch_bounds__(256)
vq_pack_kernel(const float* __restrict__ cb, float* __restrict__ ws) {
  const int e = blockIdx.x * 256 + threadIdx.x;   // 0..8191
  const int tile = e >> 7, f = (e >> 6) & 1, l = e & 63;
  const int code = tile * 16 + (l & 15);
  const int kb = f * 32 + (l >> 4) * 8;
  const float4* src = reinterpret_cast<const float4*>(cb + code * DIMV + kb);
  float4 v0 = src[0], v1 = src[1];
  float v[8] = {v0.x, v0.y, v0.z, v0.w, v1.x, v1.y, v1.z, v1.w};
  unsigned int hw[4];
#pragma unroll
  for (int j = 0; j < 4; ++j) {
    hw[j] = (unsigned int)bf16rne(v[2 * j]) |
            ((unsigned int)bf16rne(v[2 * j + 1]) << 16);
  }
  char* pack = (char*)ws + WS_PACK_BYTES;
  *(uint4*)(pack + tile * 2048 + f * 1024 + l * 16) =
      make_uint4(hw[0], hw[1], hw[2], hw[3]);
  if (e < KC) {
    float row[DIMV];
    const float4* r4 = reinterpret_cast<const float4*>(cb + e * DIMV);
#pragma unroll
    for (int i = 0; i < 16; ++i) {
      float4 t = r4[i];
      row[4 * i + 0] = t.x; row[4 * i + 1] = t.y;
      row[4 * i + 2] = t.z; row[4 * i + 3] = t.w;
    }
    ws[WS_NORM + e] = sumsq64_np(row);
  }
}

// ---------------- MFMA main kernel -----------------------------------------
__global__ void __launch_bounds__(256)
vq_main_mfma(const float* __restrict__ xin, const float* __restrict__ cb,
             float* __restrict__ out, float* __restrict__ ws) {
  __shared__ __align__(16) char s_stage[2][8192];  // 4-tile double buffer
  __shared__ float s_norm[KC];
  __shared__ unsigned int s_hist[KC];
  __shared__ float s_x[NWAVE][16][72];
  __shared__ float s_xx[TPB];
  __shared__ unsigned int s_cand[NWAVE][CMAX];
  __shared__ float s_exd[NWAVE][CMAX];
  __shared__ int s_cnt[NWAVE];

  const int tid = threadIdx.x;
  const int l   = tid & 63;
  const int wv  = tid >> 6;
  const int g   = l >> 4;
  const int cls = l & 15;
  const int blk = blockIdx.x;

  float* ws_mse = ws;
  unsigned int* ws_hist = (unsigned int*)ws + WS_HIST;
  const float* ws_norm = ws + WS_NORM;
  const char* pack = (const char*)ws + WS_PACK_BYTES;

  for (int k = tid; k < KC; k += 256) { s_norm[k] = ws_norm[k]; s_hist[k] = 0u; }
  if (tid < NWAVE) s_cnt[tid] = 0;

  // stage 64 token rows (fp32 exact) into LDS
  {
    const char* gx = (const char*)xin + (size_t)blk * (TPB * DIMV * 4);
#pragma unroll
    for (int r = 0; r < 4; ++r) {
      float4 v = *(const float4*)(gx + r * 4096 + tid * 16);
      *(float4*)&s_x[r][tid >> 4][(tid & 15) * 4] = v;
    }
  }
  __syncthreads();

  if (l < 16) {
    float row[DIMV];
    const float* xr = s_x[wv][l];
#pragma unroll
    for (int i = 0; i < DIMV; ++i) row[i] = xr[i];
    s_xx[wv * 16 + l] = sumsq64_np(row);
  }

  // A fragments (hi only): row = cls, k = f*32 + g*8 + j
  short8 ahi[2];
#pragma unroll
  for (int f = 0; f < 2; ++f) {
    const float* xr = &s_x[wv][cls][f * 32 + g * 8];
#pragma unroll
    for (int j = 0; j < 8; ++j) ahi[f][j] = (short)bf16rne(xr[j]);
  }

  // ---------------- phase 1: per-token min of s~ = norm - 2*dot~ ----------
  float minv[4] = {INFINITY, INFINITY, INFINITY, INFINITY};
  float4 st0 = *(const float4*)(pack + tid * 16);
  float4 st1 = *(const float4*)(pack + 4096 + tid * 16);
  *(float4*)(s_stage[0] + tid * 16) = st0;
  *(float4*)(s_stage[0] + 4096 + tid * 16) = st1;
  __syncthreads();
  int cur = 0;
#pragma unroll 1
  for (int ch = 0; ch < NCHUNK; ++ch) {
    if (ch < NCHUNK - 1) {
      const char* gsrc = pack + (size_t)(ch + 1) * 8192;
      st0 = *(const float4*)(gsrc + tid * 16);
      st1 = *(const float4*)(gsrc + 4096 + tid * 16);
    }
#pragma unroll
    for (int t2 = 0; t2 < 4; ++t2) {
      const char* bp = s_stage[cur] + t2 * 2048;
      short8 bh0 = *(const short8*)(bp + l * 16);
      short8 bh1 = *(const short8*)(bp + 1024 + l * 16);
      f32x4 acc = {0.0f, 0.0f, 0.0f, 0.0f};
      acc = __builtin_amdgcn_mfma_f32_16x16x32_bf16(ahi[0], bh0, acc, 0, 0, 0);
      acc = __builtin_amdgcn_mfma_f32_16x16x32_bf16(ahi[1], bh1, acc, 0, 0, 0);
      float nr = s_norm[(ch * 4 + t2) * 16 + cls];
#pragma unroll
      for (int j = 0; j < 4; ++j)
        minv[j] = fminf(minv[j], fmaf(-2.0f, acc[j], nr));
    }
    if (ch < NCHUNK - 1) {
      *(float4*)(s_stage[1 - cur] + tid * 16) = st0;
      *(float4*)(s_stage[1 - cur] + 4096 + tid * 16) = st1;
    }
    __syncthreads();
    cur ^= 1;
  }
#pragma unroll
  for (int mask = 1; mask < 16; mask <<= 1) {
#pragma unroll
    for (int j = 0; j < 4; ++j)
      minv[j] = fminf(minv[j], __shfl_xor(minv[j], mask, 64));
  }
  float thr[4];
#pragma unroll
  for (int j = 0; j < 4; ++j) thr[j] = minv[j] + EPS;

  // ---------------- phase 2: collect candidates s~ <= min + EPS -----------
  __syncthreads();
  st0 = *(const float4*)(pack + tid * 16);
  st1 = *(const float4*)(pack + 4096 + tid * 16);
  *(float4*)(s_stage[0] + tid * 16) = st0;
  *(float4*)(s_stage[0] + 4096 + tid * 16) = st1;
  __syncthreads();
  cur = 0;
#pragma unroll 1
  for (int ch = 0; ch < NCHUNK; ++ch) {
    if (ch < NCHUNK - 1) {
      const char* gsrc = pack + (size_t)(ch + 1) * 8192;
      st0 = *(const float4*)(gsrc + tid * 16);
      st1 = *(const float4*)(gsrc + 4096 + tid * 16);
    }
#pragma unroll
    for (int t2 = 0; t2 < 4; ++t2) {
      const char* bp = s_stage[cur] + t2 * 2048;
      const int tile = ch * 4 + t2;
      short8 bh0 = *(const short8*)(bp + l * 16);
      short8 bh1 = *(const short8*)(bp + 1024 + l * 16);
      f32x4 acc = {0.0f, 0.0f, 0.0f, 0.0f};
      acc = __builtin_amdgcn_mfma_f32_16x16x32_bf16(ahi[0], bh0, acc, 0, 0, 0);
      acc = __builtin_amdgcn_mfma_f32_16x16x32_bf16(ahi[1], bh1, acc, 0, 0, 0);
      float nr = s_norm[tile * 16 + cls];
      bool p = false;
      float sv[4];
#pragma unroll
      for (int j = 0; j < 4; ++j) {
        sv[j] = fmaf(-2.0f, acc[j], nr);
        p = p || (sv[j] <= thr[j]);
      }
      if (__ballot(p)) {
#pragma unroll
        for (int j = 0; j < 4; ++j) {
          if (sv[j] <= thr[j]) {
            int pos = atomicAdd(&s_cnt[wv], 1);
            if (pos < CMAX)
              s_cand[wv][pos] = ((unsigned int)(g * 4 + j) << 10) |
                                (unsigned int)(tile * 16 + cls);
          }
        }
      }
    }
    if (ch < NCHUNK - 1) {
      *(float4*)(s_stage[1 - cur] + tid * 16) = st0;
      *(float4*)(s_stage[1 - cur] + 4096 + tid * 16) = st1;
    }
    __syncthreads();
    cur ^= 1;
  }

  // ---------------- exact re-score (bit-identical fmaf chain) -------------
  int n = s_cnt[wv]; const bool ovf = (n > CMAX); if (n > CMAX) n = CMAX;
  for (int base = 0; base < n; base += 64) {
    int i = base + l;
    if (i < n) {
      unsigned int pk = s_cand[wv][i];
      int m = (int)(pk >> 10), k = (int)(pk & 1023);
      const float4* er = (const float4*)(cb + (size_t)k * DIMV);
      const float* xr = s_x[wv][m];
      float dot = 0.0f;
#pragma unroll
      for (int r = 0; r < 16; ++r) {
        float4 t = er[r];
        dot = __builtin_fmaf(t.x, xr[4 * r + 0], dot);
        dot = __builtin_fmaf(t.y, xr[4 * r + 1], dot);
        dot = __builtin_fmaf(t.z, xr[4 * r + 2], dot);
        dot = __builtin_fmaf(t.w, xr[4 * r + 3], dot);
      }
      s_exd[wv][i] = (s_xx[wv * 16 + m] - 2.0f * dot) + s_norm[k];
    }
  }

  // ---------------- merge (first-occurrence argmin) + epilogue ------------
  float mse_part = 0.0f;
  if (l < 16) {
    float bd = INFINITY; int bk = 0;
    for (int i = 0; i < n; ++i) {
      unsigned int pk = s_cand[wv][i];
      if ((int)(pk >> 10) == l) {
        float d = s_exd[wv][i]; int k = (int)(pk & 1023);
        if (d < bd || (d == bd && k < bk)) { bd = d; bk = k; }
      }
    }
    if (ovf) {  // safety net (never taken with sane data): exact full scan
      const float* xr = s_x[wv][l];
      float xx = s_xx[wv * 16 + l];
      bd = INFINITY; bk = 0;
      for (int k = 0; k < KC; ++k) {
        const float* e = cb + (size_t)k * DIMV;
        float dot = 0.0f;
#pragma unroll
        for (int i = 0; i < DIMV; ++i) dot = __builtin_fmaf(e[i], xr[i], dot);
        float d = (xx - 2.0f * dot) + s_norm[k];
        if (d < bd) { bd = d; bk = k; }
      }
    }
    const int token = blk * TPB + wv * 16 + l;
    out[OUT_IDX + token] = (float)bk;
    atomicAdd(&s_hist[bk], 1u);
    const float4* q4 = (const float4*)(cb + (size_t)bk * DIMV);
    const float* xr = s_x[wv][l];
    float* oq = out + OUT_Q + (size_t)token * DIMV;
#pragma unroll
    for (int r = 0; r < 16; ++r) {
      float4 qv = q4[r];
      float d0 = qv.x - xr[4 * r + 0];
      float d1 = qv.y - xr[4 * r + 1];
      float d2 = qv.z - xr[4 * r + 2];
      float d3 = qv.w - xr[4 * r + 3];
      float4 o;
      o.x = xr[4 * r + 0] + d0; o.y = xr[4 * r + 1] + d1;
      o.z = xr[4 * r + 2] + d2; o.w = xr[4 * r + 3] + d3;
      mse_part = __builtin_fmaf(d0, d0, mse_part);
      mse_part = __builtin_fmaf(d1, d1, mse_part);
      mse_part = __builtin_fmaf(d2, d2, mse_part);
      mse_part = __builtin_fmaf(d3, d3, mse_part);
      *(float4*)(oq + 4 * r) = o;
    }
  }
#pragma unroll
  for (int mask = 1; mask < 64; mask <<= 1)
    mse_part += __shfl_xor(mse_part, mask, 64);
  if (l == 0) atomicAdd(ws_mse, mse_part);

  __syncthreads();
  for (int k = tid; k < KC; k += 256) {
    unsigned int c = s_hist[k];
    if (c) atomicAdd(&ws_hist[k], c);
  }
}

// ---------------- fallback: verified VALU kernel (round-1, 332us) ----------
__global__ void __launch_bounds__(256)
vq_main_valu(const float* __restrict__ xin, const float* __restrict__ cb,
             float* __restrict__ out, float* __restrict__ ws) {
  __shared__ float s_norm[KC];
  __shared__ unsigned int s_hist[KC];
  __shared__ float s_cd[256];
  __shared__ int   s_ci[256];
  const int tid = threadIdx.x;
  const int lane = tid & 63;
  const int wv = __builtin_amdgcn_readfirstlane(tid >> 6);
  float* ws_mse = ws;
  unsigned int* ws_hist = (unsigned int*)ws + WS_HIST;

  for (int k = tid; k < KC; k += 256) {
    float e[DIMV];
    const float4* e4 = reinterpret_cast<const float4*>(cb + k * DIMV);
#pragma unroll
    for (int i = 0; i < 16; ++i) {
      float4 t = e4[i];
      e[4 * i + 0] = t.x; e[4 * i + 1] = t.y;
      e[4 * i + 2] = t.z; e[4 * i + 3] = t.w;
    }
    s_norm[k] = sumsq64_np(e);
    s_hist[k] = 0u;
  }
  __syncthreads();

  const int token = blockIdx.x * TPB + lane;
  float x[DIMV];
  const float4* x4 = reinterpret_cast<const float4*>(xin + (long)token * DIMV);
#pragma unroll
  for (int i = 0; i < 16; ++i) {
    float4 t = x4[i];
    x[4 * i + 0] = t.x; x[4 * i + 1] = t.y;
    x[4 * i + 2] = t.z; x[4 * i + 3] = t.w;
  }
  float xx = sumsq64_np(x);

  float best = INFINITY;
  int bidx = 0;
#pragma unroll 1
  for (int kk = 0; kk < KC / 4; ++kk) {
    const int k = wv * (KC / 4) + kk;
    const float* e = cb + k * DIMV;
    float dot = 0.0f;
#pragma unroll
    for (int i = 0; i < DIMV; ++i) dot = __builtin_fmaf(e[i], x[i], dot);
    float d = (xx - 2.0f * dot) + s_norm[k];
    if (d < best) { best = d; bidx = k; }
  }
  s_cd[tid] = best;
  s_ci[tid] = bidx;
  __syncthreads();

  if (wv == 0) {
    float bd = s_cd[lane];
    int   bi = s_ci[lane];
#pragma unroll
    for (int w = 1; w < 4; ++w) {
      float dw = s_cd[w * 64 + lane];
      int   iw = s_ci[w * 64 + lane];
      if (dw < bd) { bd = dw; bi = iw; }
    }
    out[OUT_IDX + token] = (float)bi;
    atomicAdd(&s_hist[bi], 1u);
    const float4* q4 = (const float4*)(cb + (long)bi * DIMV);
    float acc = 0.0f;
    float4* oq4 = reinterpret_cast<float4*>(out + OUT_Q + (long)token * DIMV);
#pragma unroll
    for (int i = 0; i < 16; ++i) {
      float4 qv = q4[i];
      float d0 = qv.x - x[4 * i + 0];
      float d1 = qv.y - x[4 * i + 1];
      float d2 = qv.z - x[4 * i + 2];
      float d3 = qv.w - x[4 * i + 3];
      float4 o;
      o.x = x[4 * i + 0] + d0; o.y = x[4 * i + 1] + d1;
      o.z = x[4 * i + 2] + d2; o.w = x[4 * i + 3] + d3;
      acc = __builtin_fmaf(d0, d0, acc);
      acc = __builtin_fmaf(d1, d1, acc);
      acc = __builtin_fmaf(d2, d2, acc);
      acc = __builtin_fmaf(d3, d3, acc);
      oq4[i] = o;
    }
#pragma unroll
    for (int off = 32; off > 0; off >>= 1) acc += __shfl_down(acc, off, 64);
    if (lane == 0) atomicAdd(ws_mse, acc);
  }
  __syncthreads();
  for (int k = tid; k < KC; k += 256) {
    unsigned int c = s_hist[k];
    if (c) atomicAdd(&ws_hist[k], c);
  }
}

__global__ void __launch_bounds__(1024)
vq_final_kernel(const unsigned int* __restrict__ ws_hist,
                const float* __restrict__ ws_mse,
                float* __restrict__ out) {
  __shared__ float s_red[1024];
  const int t = threadIdx.x;
  float p = (float)ws_hist[t] / 131072.0f;
  float term = p * logf(p + 1e-10f);
  s_red[t] = term;
  __syncthreads();
#pragma unroll
  for (int s = 512; s > 0; s >>= 1) {
    if (t < s) s_red[t] += s_red[t + s];
    __syncthreads();
  }
  if (t == 0) {
    out[OUT_PERP] = expf(-s_red[0]);
    float mse = ws_mse[0] / 8388608.0f;
    out[OUT_LOSS] = mse + 0.25f * mse;
  }
}

extern "C" void kernel_launch(void* const* d_in, const int* in_sizes, int n_in,
                              void* d_out, int out_size, void* d_ws, size_t ws_size,
                              hipStream_t stream) {
  (void)in_sizes; (void)n_in; (void)out_size;
  const float* xin = (const float*)d_in[0];
  const float* cb  = (const float*)d_in[1];
  float* out = (float*)d_out;
  float* ws  = (float*)d_ws;

  hipMemsetAsync(d_ws, 0, sizeof(float) * (1 + KC), stream);
  if (ws_size >= (size_t)(WS_NEED + 256)) {
    hipLaunchKernelGGL(vq_pack_kernel, dim3(32), dim3(256), 0, stream, cb, ws);
    hipLaunchKernelGGL(vq_main_mfma, dim3(NTOK / TPB), dim3(256), 0, stream,
                       xin, cb, out, ws);
  } else {
    hipLaunchKernelGGL(vq_main_valu, dim3(NTOK / TPB), dim3(256), 0, stream,
                       xin, cb, out, ws);
  }
  hipLaunchKernelGGL(vq_final_kernel, dim3(1), dim3(1024), 0, stream,
                     (const unsigned int*)ws + WS_HIST, ws, out);
}

// Round 4
// 179.502 us; speedup vs baseline: 2.6231x; 1.4275x over previous
//
#include <hip/hip_runtime.h>
#include <math.h>

#define NTOK 131072
#define KC   1024
#define DIMV 64
#define NWAVE 16
#define TPW  32                  // tokens per wave
#define TPB  (NWAVE * TPW)       // 512 tokens per block
#define CMAX 128                 // per-wave candidate capacity (expect ~64)
#define EPS  2e-3f               // > 2*(E1+E2), E1<=6.2e-4 worst-case bf16-hi

#define OUT_LOSS 0
#define OUT_Q    1
#define OUT_PERP (1 + NTOK * DIMV)
#define OUT_IDX  (2 + NTOK * DIMV)

#define WS_HIST 1
#define WS_NORM 1025
#define WS_PACK_BYTES 12288
#define WS_NEED (WS_PACK_BYTES + KC * DIMV * 2)   // 143360 bytes

typedef __attribute__((ext_vector_type(8))) short short8;
typedef __attribute__((ext_vector_type(4))) float f32x4;

// numpy pairwise_sum mimic for n=64 of v[i]*v[i] (no FMA) — bit-identical
// to the verified kernel.
__device__ __forceinline__ float sumsq64_np(const float v[DIMV]) {
#pragma clang fp contract(off)
  {
    float r[8];
#pragma unroll
    for (int j = 0; j < 8; ++j) r[j] = v[j] * v[j];
#pragma unroll
    for (int i = 8; i < 64; i += 8) {
#pragma unroll
      for (int j = 0; j < 8; ++j) r[j] += v[i + j] * v[i + j];
    }
    return ((r[0] + r[1]) + (r[2] + r[3])) + ((r[4] + r[5]) + (r[6] + r[7]));
  }
}

__device__ __forceinline__ unsigned short bf16rne(float f) {
  unsigned int u = __float_as_uint(f);
  return (unsigned short)((u + 0x7fffu + ((u >> 16) & 1u)) >> 16);
}

// ---------------- pack: bf16-hi B-fragments + exact norms (verified) -------
// Tile t holds codes t*16..t*16+15. Consuming lane l reads code t*16+(l&15),
// k = f*32 + (l>>4)*8 + j  (B layout of mfma_f32_16x16x32_bf16).
__global__ void __launch_bounds__(256)
vq_pack_kernel(const float* __restrict__ cb, float* __restrict__ ws) {
  const int e = blockIdx.x * 256 + threadIdx.x;   // 0..8191
  const int tile = e >> 7, f = (e >> 6) & 1, l = e & 63;
  const int code = tile * 16 + (l & 15);
  const int kb = f * 32 + (l >> 4) * 8;
  const float4* src = reinterpret_cast<const float4*>(cb + code * DIMV + kb);
  float4 v0 = src[0], v1 = src[1];
  float v[8] = {v0.x, v0.y, v0.z, v0.w, v1.x, v1.y, v1.z, v1.w};
  unsigned int hw[4];
#pragma unroll
  for (int j = 0; j < 4; ++j) {
    hw[j] = (unsigned int)bf16rne(v[2 * j]) |
            ((unsigned int)bf16rne(v[2 * j + 1]) << 16);
  }
  char* pack = (char*)ws + WS_PACK_BYTES;
  *(uint4*)(pack + tile * 2048 + f * 1024 + l * 16) =
      make_uint4(hw[0], hw[1], hw[2], hw[3]);
  if (e < KC) {
    float row[DIMV];
    const float4* r4 = reinterpret_cast<const float4*>(cb + e * DIMV);
#pragma unroll
    for (int i = 0; i < 16; ++i) {
      float4 t = r4[i];
      row[4 * i + 0] = t.x; row[4 * i + 1] = t.y;
      row[4 * i + 2] = t.z; row[4 * i + 3] = t.w;
    }
    ws[WS_NORM + e] = sumsq64_np(row);
  }
}

// ---------------- MFMA main: LDS-resident codebook, barrier-free loop ------
__global__ void __launch_bounds__(1024, 4)
vq_main_mfma(const float* __restrict__ xin, const float* __restrict__ cb,
             float* __restrict__ out, float* __restrict__ ws) {
  __shared__ __align__(16) char s_pack[131072];       // 128 KB packed codebook
  __shared__ float s_norm[KC];
  __shared__ unsigned int s_hist[KC];
  __shared__ unsigned int s_cand[NWAVE][CMAX];
  __shared__ unsigned long long s_key[NWAVE][TPW];
  __shared__ int s_cnt[NWAVE];

  const int tid = threadIdx.x;
  const int l   = tid & 63;
  const int wv  = tid >> 6;
  const int cls = l & 15;     // A-row supplied / D-col (code within tile)
  const int g   = l >> 4;     // k-subgroup / D-row group
  const int blk = blockIdx.x;
  const int tb  = blk * TPB + wv * TPW;

  float* ws_mse = ws;
  unsigned int* ws_hist = (unsigned int*)ws + WS_HIST;
  const float* ws_norm = ws + WS_NORM;
  const char* pack = (const char*)ws + WS_PACK_BYTES;

  // ---- prologue: stage pack (128 KB) + norms; init hist/keys/cnt ----
  {
    const uint4* src = (const uint4*)pack;
    uint4* dst = (uint4*)s_pack;
#pragma unroll
    for (int i = 0; i < 8; ++i) dst[tid + i * 1024] = src[tid + i * 1024];
  }
  s_norm[tid] = ws_norm[tid];
  s_hist[tid] = 0u;
  if (tid < NWAVE * TPW) s_key[tid >> 5][tid & 31] = ~0ull;
  if (tid < NWAVE) s_cnt[tid] = 0;
  __syncthreads();

  // A-fragments (bf16-hi) for 2 token groups: row = cls, k = kc*32 + g*8 + j
  short8 af[2][2];
#pragma unroll
  for (int grp = 0; grp < 2; ++grp) {
    const float* xr = xin + (size_t)(tb + grp * 16 + cls) * DIMV + g * 8;
#pragma unroll
    for (int kc = 0; kc < 2; ++kc) {
      float4 v0 = *(const float4*)(xr + kc * 32);
      float4 v1 = *(const float4*)(xr + kc * 32 + 4);
      float vv[8] = {v0.x, v0.y, v0.z, v0.w, v1.x, v1.y, v1.z, v1.w};
#pragma unroll
      for (int j = 0; j < 8; ++j) af[grp][kc][j] = (short)bf16rne(vv[j]);
    }
  }

  // ---------------- pass 1: per-token min of s~ = norm - 2*dot~ -----------
  float minv[2][4];
#pragma unroll
  for (int grp = 0; grp < 2; ++grp)
#pragma unroll
    for (int j = 0; j < 4; ++j) minv[grp][j] = INFINITY;

#pragma unroll 1
  for (int t = 0; t < 64; ++t) {
    const char* bp = s_pack + t * 2048;
    short8 b0 = *(const short8*)(bp + l * 16);
    short8 b1 = *(const short8*)(bp + 1024 + l * 16);
    float nr = s_norm[t * 16 + cls];
#pragma unroll
    for (int grp = 0; grp < 2; ++grp) {
      f32x4 acc = {0.0f, 0.0f, 0.0f, 0.0f};
      acc = __builtin_amdgcn_mfma_f32_16x16x32_bf16(af[grp][0], b0, acc, 0, 0, 0);
      acc = __builtin_amdgcn_mfma_f32_16x16x32_bf16(af[grp][1], b1, acc, 0, 0, 0);
#pragma unroll
      for (int j = 0; j < 4; ++j)
        minv[grp][j] = fminf(minv[grp][j], fmaf(-2.0f, acc[j], nr));
    }
  }
  // reduce over the 16 code-columns (lanes sharing g): masks 1,2,4,8
#pragma unroll
  for (int mask = 1; mask < 16; mask <<= 1) {
#pragma unroll
    for (int grp = 0; grp < 2; ++grp)
#pragma unroll
      for (int j = 0; j < 4; ++j)
        minv[grp][j] = fminf(minv[grp][j], __shfl_xor(minv[grp][j], mask, 64));
  }
  float thr[2][4];
#pragma unroll
  for (int grp = 0; grp < 2; ++grp)
#pragma unroll
    for (int j = 0; j < 4; ++j) thr[grp][j] = minv[grp][j] + EPS;

  // ---------------- pass 2: collect candidates s~ <= min + EPS ------------
#pragma unroll 1
  for (int t = 0; t < 64; ++t) {
    const char* bp = s_pack + t * 2048;
    short8 b0 = *(const short8*)(bp + l * 16);
    short8 b1 = *(const short8*)(bp + 1024 + l * 16);
    float nr = s_norm[t * 16 + cls];
#pragma unroll
    for (int grp = 0; grp < 2; ++grp) {
      f32x4 acc = {0.0f, 0.0f, 0.0f, 0.0f};
      acc = __builtin_amdgcn_mfma_f32_16x16x32_bf16(af[grp][0], b0, acc, 0, 0, 0);
      acc = __builtin_amdgcn_mfma_f32_16x16x32_bf16(af[grp][1], b1, acc, 0, 0, 0);
#pragma unroll
      for (int j = 0; j < 4; ++j) {
        float sv = fmaf(-2.0f, acc[j], nr);
        if (sv <= thr[grp][j]) {
          int pos = atomicAdd(&s_cnt[wv], 1);
          if (pos < CMAX)
            s_cand[wv][pos] =
                ((unsigned int)(grp * 16 + g * 4 + j) << 10) |
                (unsigned int)(t * 16 + cls);
        }
      }
    }
  }
  asm volatile("s_waitcnt lgkmcnt(0)" ::: "memory");
  const int cnt = s_cnt[wv];
  int n = cnt < CMAX ? cnt : CMAX;

  // ---------------- exact re-score (bit-identical chains) -----------------
  for (int base = 0; base < n; base += 64) {
    int i = base + l;
    if (i < n) {
      unsigned int pk = s_cand[wv][i];
      int m = (int)(pk >> 10), k = (int)(pk & 1023);
      const float4* xr4 = (const float4*)(xin + (size_t)(tb + m) * DIMV);
      const float4* er4 = (const float4*)(cb + (size_t)k * DIMV);
      float r[8];
      float dot = 0.0f;
#pragma unroll
      for (int s = 0; s < 8; ++s) {
        float4 a = xr4[2 * s], b = xr4[2 * s + 1];
        float4 ea = er4[2 * s], eb = er4[2 * s + 1];
        float xv[8] = {a.x, a.y, a.z, a.w, b.x, b.y, b.z, b.w};
        float ev[8] = {ea.x, ea.y, ea.z, ea.w, eb.x, eb.y, eb.z, eb.w};
        {
#pragma clang fp contract(off)
#pragma unroll
          for (int j = 0; j < 8; ++j) {
            float sq = xv[j] * xv[j];
            r[j] = (s == 0) ? sq : (r[j] + sq);
          }
        }
#pragma unroll
        for (int j = 0; j < 8; ++j) dot = __builtin_fmaf(ev[j], xv[j], dot);
      }
      float xx = ((r[0] + r[1]) + (r[2] + r[3])) + ((r[4] + r[5]) + (r[6] + r[7]));
      float d = (xx - 2.0f * dot) + s_norm[k];
      unsigned long long key =
          ((unsigned long long)__float_as_uint(d) << 10) | (unsigned long long)k;
      atomicMin(&s_key[wv][m], key);
    }
  }

  // safety net (never expected): candidate overflow -> exact full scan
  if (cnt > CMAX) {
    if (l < TPW) {
      const int m = l;
      float xv[DIMV];
      const float4* xr4 = (const float4*)(xin + (size_t)(tb + m) * DIMV);
#pragma unroll
      for (int i = 0; i < 16; ++i) {
        float4 t4 = xr4[i];
        xv[4 * i + 0] = t4.x; xv[4 * i + 1] = t4.y;
        xv[4 * i + 2] = t4.z; xv[4 * i + 3] = t4.w;
      }
      float xx = sumsq64_np(xv);
      float bd = INFINITY; int bk = 0;
      for (int k = 0; k < KC; ++k) {
        const float* e = cb + (size_t)k * DIMV;
        float dot = 0.0f;
#pragma unroll
        for (int i = 0; i < DIMV; ++i) dot = __builtin_fmaf(e[i], xv[i], dot);
        float d = (xx - 2.0f * dot) + s_norm[k];
        if (d < bd) { bd = d; bk = k; }
      }
      s_key[wv][m] =
          ((unsigned long long)__float_as_uint(bd) << 10) | (unsigned long long)bk;
    }
  }
  asm volatile("s_waitcnt lgkmcnt(0)" ::: "memory");

  // ---------------- epilogue: idx, quantized_st, mse, hist ----------------
  {
    const int m = l & 31, h = l >> 5;
    const int token = tb + m;
    unsigned long long key = s_key[wv][m];
    const int bk = (int)(key & 1023ull);
    if (h == 0) {
      out[OUT_IDX + token] = (float)bk;
      atomicAdd(&s_hist[bk], 1u);
    }
    const float4* q4 = (const float4*)(cb + (size_t)bk * DIMV + h * 32);
    const float4* x4 = (const float4*)(xin + (size_t)token * DIMV + h * 32);
    float* oq = out + OUT_Q + (size_t)token * DIMV + h * 32;
    float mse_part = 0.0f;
#pragma unroll
    for (int rr = 0; rr < 8; ++rr) {
      float4 qv = q4[rr], xv = x4[rr];
      float d0 = qv.x - xv.x, d1 = qv.y - xv.y;
      float d2 = qv.z - xv.z, d3 = qv.w - xv.w;
      float4 o;
      o.x = xv.x + d0; o.y = xv.y + d1; o.z = xv.z + d2; o.w = xv.w + d3;
      mse_part = __builtin_fmaf(d0, d0, mse_part);
      mse_part = __builtin_fmaf(d1, d1, mse_part);
      mse_part = __builtin_fmaf(d2, d2, mse_part);
      mse_part = __builtin_fmaf(d3, d3, mse_part);
      *(float4*)(oq + 4 * rr) = o;
    }
#pragma unroll
    for (int mask = 1; mask < 64; mask <<= 1)
      mse_part += __shfl_xor(mse_part, mask, 64);
    if (l == 0) atomicAdd(ws_mse, mse_part);
  }

  __syncthreads();
  {
    unsigned int c = s_hist[tid];
    if (c) atomicAdd(&ws_hist[tid], c);
  }
}

// ---------------- fallback: verified VALU kernel (round-1, 332us) ----------
__global__ void __launch_bounds__(256)
vq_main_valu(const float* __restrict__ xin, const float* __restrict__ cb,
             float* __restrict__ out, float* __restrict__ ws) {
  __shared__ float s_norm[KC];
  __shared__ unsigned int s_hist[KC];
  __shared__ float s_cd[256];
  __shared__ int   s_ci[256];
  const int tid = threadIdx.x;
  const int lane = tid & 63;
  const int wv = __builtin_amdgcn_readfirstlane(tid >> 6);
  float* ws_mse = ws;
  unsigned int* ws_hist = (unsigned int*)ws + WS_HIST;

  for (int k = tid; k < KC; k += 256) {
    float e[DIMV];
    const float4* e4 = reinterpret_cast<const float4*>(cb + k * DIMV);
#pragma unroll
    for (int i = 0; i < 16; ++i) {
      float4 t = e4[i];
      e[4 * i + 0] = t.x; e[4 * i + 1] = t.y;
      e[4 * i + 2] = t.z; e[4 * i + 3] = t.w;
    }
    s_norm[k] = sumsq64_np(e);
    s_hist[k] = 0u;
  }
  __syncthreads();

  const int token = blockIdx.x * 64 + lane;
  float x[DIMV];
  const float4* x4 = reinterpret_cast<const float4*>(xin + (long)token * DIMV);
#pragma unroll
  for (int i = 0; i < 16; ++i) {
    float4 t = x4[i];
    x[4 * i + 0] = t.x; x[4 * i + 1] = t.y;
    x[4 * i + 2] = t.z; x[4 * i + 3] = t.w;
  }
  float xx = sumsq64_np(x);

  float best = INFINITY;
  int bidx = 0;
#pragma unroll 1
  for (int kk = 0; kk < KC / 4; ++kk) {
    const int k = wv * (KC / 4) + kk;
    const float* e = cb + k * DIMV;
    float dot = 0.0f;
#pragma unroll
    for (int i = 0; i < DIMV; ++i) dot = __builtin_fmaf(e[i], x[i], dot);
    float d = (xx - 2.0f * dot) + s_norm[k];
    if (d < best) { best = d; bidx = k; }
  }
  s_cd[tid] = best;
  s_ci[tid] = bidx;
  __syncthreads();

  if (wv == 0) {
    float bd = s_cd[lane];
    int   bi = s_ci[lane];
#pragma unroll
    for (int w = 1; w < 4; ++w) {
      float dw = s_cd[w * 64 + lane];
      int   iw = s_ci[w * 64 + lane];
      if (dw < bd) { bd = dw; bi = iw; }
    }
    out[OUT_IDX + token] = (float)bi;
    atomicAdd(&s_hist[bi], 1u);
    const float4* q4 = (const float4*)(cb + (long)bi * DIMV);
    float acc = 0.0f;
    float4* oq4 = reinterpret_cast<float4*>(out + OUT_Q + (long)token * DIMV);
#pragma unroll
    for (int i = 0; i < 16; ++i) {
      float4 qv = q4[i];
      float d0 = qv.x - x[4 * i + 0];
      float d1 = qv.y - x[4 * i + 1];
      float d2 = qv.z - x[4 * i + 2];
      float d3 = qv.w - x[4 * i + 3];
      float4 o;
      o.x = x[4 * i + 0] + d0; o.y = x[4 * i + 1] + d1;
      o.z = x[4 * i + 2] + d2; o.w = x[4 * i + 3] + d3;
      acc = __builtin_fmaf(d0, d0, acc);
      acc = __builtin_fmaf(d1, d1, acc);
      acc = __builtin_fmaf(d2, d2, acc);
      acc = __builtin_fmaf(d3, d3, acc);
      oq4[i] = o;
    }
#pragma unroll
    for (int off = 32; off > 0; off >>= 1) acc += __shfl_down(acc, off, 64);
    if (lane == 0) atomicAdd(ws_mse, acc);
  }
  __syncthreads();
  for (int k = tid; k < KC; k += 256) {
    unsigned int c = s_hist[k];
    if (c) atomicAdd(&ws_hist[k], c);
  }
}

__global__ void __launch_bounds__(1024)
vq_final_kernel(const unsigned int* __restrict__ ws_hist,
                const float* __restrict__ ws_mse,
                float* __restrict__ out) {
  __shared__ float s_red[1024];
  const int t = threadIdx.x;
  float p = (float)ws_hist[t] / 131072.0f;
  float term = p * logf(p + 1e-10f);
  s_red[t] = term;
  __syncthreads();
#pragma unroll
  for (int s = 512; s > 0; s >>= 1) {
    if (t < s) s_red[t] += s_red[t + s];
    __syncthreads();
  }
  if (t == 0) {
    out[OUT_PERP] = expf(-s_red[0]);
    float mse = ws_mse[0] / 8388608.0f;
    out[OUT_LOSS] = mse + 0.25f * mse;
  }
}

extern "C" void kernel_launch(void* const* d_in, const int* in_sizes, int n_in,
                              void* d_out, int out_size, void* d_ws, size_t ws_size,
                              hipStream_t stream) {
  (void)in_sizes; (void)n_in; (void)out_size;
  const float* xin = (const float*)d_in[0];
  const float* cb  = (const float*)d_in[1];
  float* out = (float*)d_out;
  float* ws  = (float*)d_ws;

  hipMemsetAsync(d_ws, 0, sizeof(float) * (1 + KC), stream);
  if (ws_size >= (size_t)(WS_NEED + 256)) {
    hipLaunchKernelGGL(vq_pack_kernel, dim3(32), dim3(256), 0, stream, cb, ws);
    hipLaunchKernelGGL(vq_main_mfma, dim3(NTOK / TPB), dim3(1024), 0, stream,
                       xin, cb, out, ws);
  } else {
    hipLaunchKernelGGL(vq_main_valu, dim3(NTOK / 64), dim3(256), 0, stream,
                       xin, cb, out, ws);
  }
  hipLaunchKernelGGL(vq_final_kernel, dim3(1), dim3(1024), 0, stream,
                     (const unsigned int*)ws + WS_HIST, ws, out);
}